// Round 27
// baseline (444.671 us; speedup 1.0000x reference)
//
#include <hip/hip_runtime.h>

#define BB 8
#define NN 2048
#define HH 4
#define EE 64
#define MAXJ 128
#define NEG 0.2f
#define NBLK 2048

static constexpr int OFF_CSRC  = 0;                      // [4]
static constexpr int OFF_CTGT  = 4;                      // [4]
static constexpr int OFF_WGWST = 8;                      // [4][64]
static constexpr int OFF_S     = 264;                    // [8]
static constexpr int OFF_SWS   = 288;                    // [N][64]
static constexpr int OFF_PART  = OFF_SWS + NN * EE;      // [N][512]
static constexpr int OFF_PART2 = OFF_PART + NN * 512;    // [256][512]
static constexpr int OFF_BAR   = OFF_PART2 + 256 * 512;  // int cnt, gen

// ---- sws: 16 rows/block, staged WsT; block 0 does prep + zeroes barrier ----
__global__ __launch_bounds__(256) void k_sws(const float* __restrict__ strucEmb,
                                             const float* __restrict__ Ws,
                                             const float* __restrict__ W_gat,
                                             const float* __restrict__ att,
                                             const float* __restrict__ Wst,
                                             float* __restrict__ ws) {
    __shared__ float s_wsT[EE * 65];
    __shared__ float s_emb[16 * EE];
    const int t = threadIdx.x;
    const int w = t >> 6, lane = t & 63;
    const int i0 = blockIdx.x * 16;
    for (int k = t; k < EE * EE; k += 256)
        s_wsT[(k & 63) * 65 + (k >> 6)] = Ws[k];
    for (int k = t; k < 16 * EE; k += 256)
        s_emb[k] = strucEmb[(size_t)i0 * EE + k];
    __syncthreads();
    for (int q = 0; q < 4; ++q) {
        int r = w * 4 + q;
        float v = s_emb[r * EE + lane];
        float acc = 0.f;
        for (int e = 0; e < EE; ++e)
            acc += __shfl(v, e) * s_wsT[e * 65 + lane];
        ws[OFF_SWS + (size_t)(i0 + r) * EE + lane] = acc;
    }
    if (blockIdx.x == 0) {
        int h = t >> 6, f = t & 63;
        float acc = 0.f;
        for (int e = 0; e < EE; ++e) acc += W_gat[h * EE + e] * Wst[f * EE + e];
        ws[OFF_WGWST + t] = acc;
        if (t < 2 * HH) {
            int hh = t & 3;
            const float* wgx = W_gat + hh * EE;
            const float* av  = att + hh * 2 * EE + (t >= HH ? EE : 0);
            float a2 = 0.f;
            for (int e = 0; e < EE; ++e) a2 += wgx[e] * av[e];
            if (t < HH) ws[OFF_CSRC + hh] = a2; else ws[OFF_CTGT + hh] = a2;
        }
        if (t == 0) { ((int*)(ws + OFF_BAR))[0] = 0; ((int*)(ws + OFF_BAR))[1] = 0; }
    }
}

__device__ __forceinline__ void gbar(int* cnt, int* gen) {
    __syncthreads();
    if (threadIdx.x == 0) {
        int g = atomicAdd(gen, 0);
        __threadfence();
        if (atomicAdd(cnt, 1) == NBLK - 1) {
            atomicExch(cnt, 0);
            __threadfence();
            atomicAdd(gen, 1);
        } else {
            int spins = 0;
            while (atomicAdd(gen, 0) == g && spins < (1 << 20)) {
                __builtin_amdgcn_s_sleep(2);
                ++spins;
            }
        }
        __threadfence();
    }
    __syncthreads();
}

// ---- mega: 2048 blocks (8/CU, co-resident), grid-synced phases ----
__global__ __launch_bounds__(256, 8) void mega(
    const int* __restrict__ adj, const float* __restrict__ state,
    const float* __restrict__ l1w, const float* __restrict__ l1b,
    const float* __restrict__ l2w, const float* __restrict__ l2b,
    const float* __restrict__ l3w, const float* __restrict__ l3b,
    float* __restrict__ ws, float* __restrict__ out)
{
    __shared__ float s_buf[EE * 65];   // P1: jq/jl/y | P3: l1T | P4: l2T
    __shared__ float s_wgw[HH * EE];   // 0.25-folded, persists
    __shared__ float red[256];         // P3 tree; P4: l2b/l3 alias
    __shared__ float s_satt[32];       // persists P1->P4
    __shared__ float s_sws[EE];        // persists P1->P4
    __shared__ float s_se[EE];
    __shared__ float s_S[BB];
    __shared__ int   s_c[4];
    __shared__ int   s_cnt;

    const int i = blockIdx.x;
    const int t = threadIdx.x;
    const int w = t >> 6, lane = t & 63;
    int* bar = (int*)(ws + OFF_BAR);
    int*   jq = (int*)s_buf;           // [4][128]
    int*   jl = (int*)s_buf + 512;     // [128]
    float* yy = s_buf + 640;           // [8][128]

    s_wgw[t] = 0.25f * ws[OFF_WGWST + t];
    if (t < EE) s_sws[t] = ws[OFF_SWS + (size_t)i * EE + t];

    // ---- P1: scan (vectorized, r24-proven) ----
    {
        const int4* a4 = (const int4*)(adj + (size_t)i * NN) + w * 128;
        int base = 0;
        const unsigned long long below = (1ull << lane) - 1ull;
        for (int q = 0; q < 2; ++q) {
            int4 v = a4[q * 64 + lane];
            int j0 = w * 512 + (q * 64 + lane) * 4;
            int eb = (v.x == 0 ? 1 : 0) | (v.y == 0 ? 2 : 0) |
                     (v.z == 0 ? 4 : 0) | (v.w == 0 ? 8 : 0);
            unsigned long long b0 = __ballot(eb & 1), b1 = __ballot(eb & 2);
            unsigned long long b2 = __ballot(eb & 4), b3 = __ballot(eb & 8);
            int pos = base + __popcll(b0 & below) + __popcll(b1 & below)
                           + __popcll(b2 & below) + __popcll(b3 & below);
            if (eb & 1) { if (pos < MAXJ) jq[w * MAXJ + pos] = j0 + 0; ++pos; }
            if (eb & 2) { if (pos < MAXJ) jq[w * MAXJ + pos] = j0 + 1; ++pos; }
            if (eb & 4) { if (pos < MAXJ) jq[w * MAXJ + pos] = j0 + 2; ++pos; }
            if (eb & 8) { if (pos < MAXJ) jq[w * MAXJ + pos] = j0 + 3; ++pos; }
            base += __popcll(b0) + __popcll(b1) + __popcll(b2) + __popcll(b3);
        }
        if (lane == 0) s_c[w] = base > MAXJ ? MAXJ : base;
    }
    __syncthreads();
    {
        int start = 0;
        for (int q = 0; q < w; ++q) start += s_c[q];
        int cw = s_c[w];
        for (int k = lane; k < cw; k += 64) {
            int p = start + k;
            if (p < MAXJ) jl[p] = jq[w * MAXJ + k];
        }
        if (t == 0) {
            int tot = s_c[0] + s_c[1] + s_c[2] + s_c[3];
            s_cnt = tot > MAXJ ? MAXJ : tot;
        }
    }
    __syncthreads();
    const int cnt = s_cnt;
    for (int x = t; x < BB * MAXJ; x += 256) {
        int k = x & (MAXJ - 1);
        if (k < cnt) yy[x] = state[(x >> 7) * NN + jl[k]];
    }
    __syncthreads();
    {
        int g = t >> 3, k0 = t & 7, b = g >> 2, h = g & 3;
        const float* yb = yy + b * MAXJ;
        float ct = ws[OFF_CTGT + h];
        float si = state[b * NN + i] * ws[OFF_CSRC + h];
        float mmax = -1e30f;
        for (int k = k0; k < cnt; k += 8) {
            float e = si + ct * yb[k]; e = e > 0.f ? e : NEG * e;
            mmax = fmaxf(mmax, e);
        }
        for (int o = 4; o; o >>= 1) mmax = fmaxf(mmax, __shfl_xor(mmax, o, 8));
        float den = 0.f, num = 0.f;
        for (int k = k0; k < cnt; k += 8) {
            float y = yb[k];
            float e = si + ct * y; e = e > 0.f ? e : NEG * e;
            float p = expf(e - mmax);
            den += p; num += p * y;
        }
        for (int o = 4; o; o >>= 1) { den += __shfl_xor(den, o, 8); num += __shfl_xor(num, o, 8); }
        if (k0 == 0) s_satt[g] = num / den;
    }
    __syncthreads();
    for (int q = 0; q < 2; ++q) {
        int idx = q * 256 + t, b = idx >> 6, f = idx & 63;
        float x = s_sws[f];
        for (int h = 0; h < HH; ++h)
            x += s_satt[b * 4 + h] * s_wgw[h * EE + f];
        ws[OFF_PART + (size_t)i * 512 + idx] = fmaxf(x, 0.f);
    }
    gbar(bar, bar + 1);

    // ---- P2: 256 blocks fold 8 rows each ----
    if (i < 256) {
        float a0 = 0.f, a1 = 0.f;
        for (int r = 0; r < 8; ++r) {
            const float* p = ws + OFF_PART + (size_t)(i * 8 + r) * 512;
            a0 += p[t]; a1 += p[256 + t];
        }
        ws[OFF_PART2 + (size_t)i * 512 + t]       = a0;
        ws[OFF_PART2 + (size_t)i * 512 + 256 + t] = a1;
    }
    gbar(bar, bar + 1);

    // ---- P3: 8 blocks compute S[b] ----
    if (i < 8) {
        for (int k = t; k < EE * EE; k += 256) {
            int o = k >> 6, f2 = k & 63;
            s_buf[f2 * 65 + o] = l1w[k];
        }
        int sl = t >> 6, f = t & 63;
        float a = 0.f;
        for (int c = sl; c < 256; c += 4)
            a += ws[OFF_PART2 + (size_t)c * 512 + i * 64 + f];
        red[t] = a;
        __syncthreads();
        if (t < EE) s_se[t] = red[t] + red[64 + t] + red[128 + t] + red[192 + t];
        __syncthreads();
        if (t < EE) {
            float bs = l1b[t];
            for (int f2 = 0; f2 < EE; ++f2) bs += s_se[f2] * s_buf[f2 * 65 + t];
            float r2 = fmaxf(bs, 0.f) * l3w[t];
            for (int o = 32; o; o >>= 1) r2 += __shfl_xor(r2, o);
            if (t == 0) ws[OFF_S + i] = r2 + l3b[0];
        }
    }
    gbar(bar, bar + 1);

    // ---- P4: per-row epilogue ----
    for (int k = t; k < EE * EE; k += 256) {
        int fp = k >> 6, f = k & 63;
        s_buf[f * 65 + fp] = l2w[k];
    }
    float* l2b_s = red;
    float* l3_s  = red + 64;
    if (t < EE) { l2b_s[t] = l2b[t]; l3_s[t] = l3w[EE + t]; }
    if (t < BB) s_S[t] = ws[OFF_S + t];
    __syncthreads();
    for (int p = 0; p < 2; ++p) {
        int b = p * 4 + w;
        float xv = s_sws[lane];
        for (int h = 0; h < HH; ++h)
            xv += s_satt[b * 4 + h] * s_wgw[h * EE + lane];
        xv = fmaxf(xv, 0.f);
        float acc = l2b_s[lane];
        for (int f = 0; f < EE; ++f) acc += __shfl(xv, f) * s_buf[f * 65 + lane];
        float r2 = fmaxf(acc, 0.f) * l3_s[lane];
        for (int o = 32; o; o >>= 1) r2 += __shfl_xor(r2, o);
        if (lane == 0) out[(size_t)b * NN + i] = s_S[b] + r2;
    }
}

extern "C" void kernel_launch(void* const* d_in, const int* in_sizes, int n_in,
                              void* d_out, int out_size, void* d_ws, size_t ws_size,
                              hipStream_t stream) {
    const float* state    = (const float*)d_in[0];
    const float* strucEmb = (const float*)d_in[1];
    const int*   adj      = (const int*)d_in[2];   // int32 {0,1}, verified r11/r13
    const float* W_gat    = (const float*)d_in[3];
    const float* att      = (const float*)d_in[4];
    const float* Ws       = (const float*)d_in[5];
    const float* Wst      = (const float*)d_in[6];
    const float* lin1_w   = (const float*)d_in[7];
    const float* lin1_b   = (const float*)d_in[8];
    const float* lin2_w   = (const float*)d_in[9];
    const float* lin2_b   = (const float*)d_in[10];
    const float* lin3_w   = (const float*)d_in[11];
    const float* lin3_b   = (const float*)d_in[12];
    float* ws = (float*)d_ws;
    float* out = (float*)d_out;   // f32 output, verified r13

    k_sws<<<dim3(NN / 16), dim3(256), 0, stream>>>(strucEmb, Ws, W_gat, att, Wst, ws);
    mega <<<dim3(NBLK),    dim3(256), 0, stream>>>(adj, state,
        lin1_w, lin1_b, lin2_w, lin2_b, lin3_w, lin3_b, ws, out);
}

// Round 28
// 64.155 us; speedup vs baseline: 6.9313x; 6.9313x over previous
//
#include <hip/hip_runtime.h>

#define BB 8
#define NN 2048
#define HH 4
#define EE 64
#define MAXJ 128
#define NEG 0.2f
#define NCHUNK 32

static constexpr int OFF_CSRC  = 0;                          // [4]
static constexpr int OFF_CTGT  = 4;                          // [4]
static constexpr int OFF_WGWST = 8;                          // [4][64]
static constexpr int OFF_S     = 264;                        // [8]
static constexpr int OFF_CNT   = 272;                        // int[8]
static constexpr int OFF_SWS   = 288;                        // [N][64]
static constexpr int OFF_SATT  = OFF_SWS + NN * EE;          // [N][32]
static constexpr int OFF_PART  = OFF_SATT + NN * 32;         // [NCHUNK*B][64]

// ---- sws: 16 rows/block, staged WsT; block 0 does prep + zeroes cnt ----
__global__ __launch_bounds__(256) void k_sws(const float* __restrict__ strucEmb,
                                             const float* __restrict__ Ws,
                                             const float* __restrict__ W_gat,
                                             const float* __restrict__ att,
                                             const float* __restrict__ Wst,
                                             float* __restrict__ ws) {
    __shared__ float s_wsT[EE * 65];
    __shared__ float s_emb[16 * EE];
    const int t = threadIdx.x;
    const int w = t >> 6, lane = t & 63;
    const int i0 = blockIdx.x * 16;
    for (int k = t; k < EE * EE; k += 256)
        s_wsT[(k & 63) * 65 + (k >> 6)] = Ws[k];
    for (int k = t; k < 16 * EE; k += 256)
        s_emb[k] = strucEmb[(size_t)i0 * EE + k];
    __syncthreads();
    for (int q = 0; q < 4; ++q) {
        int r = w * 4 + q;
        float v = s_emb[r * EE + lane];
        float acc = 0.f;
        for (int e = 0; e < EE; ++e)
            acc += __shfl(v, e) * s_wsT[e * 65 + lane];
        ws[OFF_SWS + (size_t)(i0 + r) * EE + lane] = acc;
    }
    if (blockIdx.x == 0) {
        int h = t >> 6, f = t & 63;
        float acc = 0.f;
        for (int e = 0; e < EE; ++e) acc += W_gat[h * EE + e] * Wst[f * EE + e];
        ws[OFF_WGWST + t] = acc;
        if (t < 2 * HH) {
            int hh = t & 3;
            const float* wgx = W_gat + hh * EE;
            const float* av  = att + hh * 2 * EE + (t >= HH ? EE : 0);
            float a2 = 0.f;
            for (int e = 0; e < EE; ++e) a2 += wgx[e] * av[e];
            if (t < HH) ws[OFF_CSRC + hh] = a2; else ws[OFF_CTGT + hh] = a2;
        }
        if (t < BB) ((int*)(ws + OFF_CNT))[t] = 0;
    }
}

// ---- fsatt: vectorized 4-wave scan + gather + sparse softmax (r24-proven) ----
__global__ __launch_bounds__(256) void k_fsatt(const int* __restrict__ adj,
                                               const float* __restrict__ state,
                                               float* __restrict__ ws) {
    __shared__ int   s_jq[4][MAXJ];
    __shared__ int   s_c[4];
    __shared__ int   s_jl[MAXJ];
    __shared__ int   s_cnt;
    __shared__ float s_y[BB * MAXJ];
    const int i = blockIdx.x;
    const int t = threadIdx.x;
    const int w = t >> 6, lane = t & 63;

    {
        const int4* a4 = (const int4*)(adj + (size_t)i * NN) + w * 128;
        int base = 0;
        const unsigned long long below = (1ull << lane) - 1ull;
        for (int q = 0; q < 2; ++q) {
            int4 v = a4[q * 64 + lane];
            int j0 = w * 512 + (q * 64 + lane) * 4;
            int eb = (v.x == 0 ? 1 : 0) | (v.y == 0 ? 2 : 0) |
                     (v.z == 0 ? 4 : 0) | (v.w == 0 ? 8 : 0);
            unsigned long long b0 = __ballot(eb & 1), b1 = __ballot(eb & 2);
            unsigned long long b2 = __ballot(eb & 4), b3 = __ballot(eb & 8);
            int pos = base + __popcll(b0 & below) + __popcll(b1 & below)
                           + __popcll(b2 & below) + __popcll(b3 & below);
            if (eb & 1) { if (pos < MAXJ) s_jq[w][pos] = j0 + 0; ++pos; }
            if (eb & 2) { if (pos < MAXJ) s_jq[w][pos] = j0 + 1; ++pos; }
            if (eb & 4) { if (pos < MAXJ) s_jq[w][pos] = j0 + 2; ++pos; }
            if (eb & 8) { if (pos < MAXJ) s_jq[w][pos] = j0 + 3; ++pos; }
            base += __popcll(b0) + __popcll(b1) + __popcll(b2) + __popcll(b3);
        }
        if (lane == 0) s_c[w] = base > MAXJ ? MAXJ : base;
    }
    __syncthreads();
    {
        int start = 0;
        for (int q = 0; q < w; ++q) start += s_c[q];
        int cw = s_c[w];
        for (int k = lane; k < cw; k += 64) {
            int p = start + k;
            if (p < MAXJ) s_jl[p] = s_jq[w][k];
        }
        if (t == 0) {
            int tot = s_c[0] + s_c[1] + s_c[2] + s_c[3];
            s_cnt = tot > MAXJ ? MAXJ : tot;
        }
    }
    __syncthreads();
    const int cnt = s_cnt;

    for (int x = t; x < BB * MAXJ; x += 256) {
        int k = x & (MAXJ - 1);
        if (k < cnt) s_y[x] = state[(x >> 7) * NN + s_jl[k]];
    }
    __syncthreads();

    int g = t >> 3, k0 = t & 7, b = g >> 2, h = g & 3;
    const float* yb = s_y + b * MAXJ;
    float ct = ws[OFF_CTGT + h];
    float si = state[b * NN + i] * ws[OFF_CSRC + h];
    float mmax = -1e30f;
    for (int k = k0; k < cnt; k += 8) {
        float e = si + ct * yb[k]; e = e > 0.f ? e : NEG * e;
        mmax = fmaxf(mmax, e);
    }
    for (int o = 4; o; o >>= 1) mmax = fmaxf(mmax, __shfl_xor(mmax, o, 8));
    float den = 0.f, num = 0.f;
    for (int k = k0; k < cnt; k += 8) {
        float y = yb[k];
        float e = si + ct * y; e = e > 0.f ? e : NEG * e;
        float p = expf(e - mmax);
        den += p; num += p * y;
    }
    for (int o = 4; o; o >>= 1) { den += __shfl_xor(den, o, 8); num += __shfl_xor(num, o, 8); }
    if (k0 == 0) ws[OFF_SATT + i * 32 + g] = num / den;
}

// ---- fused se + S: partials, then last-block-per-b folds (fixed order) ----
__global__ __launch_bounds__(256) void k_seS(const float* __restrict__ lin1_w,
                                             const float* __restrict__ lin1_b,
                                             const float* __restrict__ lin3_w,
                                             const float* __restrict__ lin3_b,
                                             float* __restrict__ ws) {
    __shared__ float red[256];
    __shared__ float s_l1T[EE * 65];
    __shared__ float s_se[EE];
    __shared__ int   s_last;
    int b = blockIdx.x & 7, chunk = blockIdx.x >> 3;
    int t = threadIdx.x; // 256
    int f = t & 63, sl = t >> 6;
    float wgw[HH];
    for (int h = 0; h < HH; ++h) wgw[h] = 0.25f * ws[OFF_WGWST + h * EE + f];
    float acc = 0.f;
    int i0 = chunk * (NN / NCHUNK);
    for (int i = i0 + sl; i < i0 + NN / NCHUNK; i += 4) {
        float v = ws[OFF_SWS + i * EE + f];
        for (int h = 0; h < HH; ++h)
            v += ws[OFF_SATT + i * 32 + b * 4 + h] * wgw[h];
        acc += fmaxf(v, 0.f);
    }
    red[t] = acc;
    __syncthreads();
    if (t < EE)
        ws[OFF_PART + (size_t)blockIdx.x * EE + t] =
            red[t] + red[t + 64] + red[t + 128] + red[t + 192];
    // release partial, count arrivals for this b
    __threadfence();
    __syncthreads();
    if (t == 0)
        s_last = (atomicAdd((int*)(ws + OFF_CNT) + b, 1) == NCHUNK - 1) ? 1 : 0;
    __syncthreads();
    if (s_last) {
        __threadfence();   // acquire: all 32 partials for b visible
        if (t < EE) {
            float se = 0.f;
            for (int c = 0; c < NCHUNK; ++c)      // fixed ascending order = k_S
                se += ws[OFF_PART + (size_t)(c * BB + b) * EE + t];
            s_se[t] = se;
        }
        for (int k = t; k < EE * EE; k += 256) {
            int o = k >> 6, f2 = k & 63;
            s_l1T[f2 * 65 + o] = lin1_w[k];
        }
        __syncthreads();
        if (t < EE) {
            float bs = lin1_b[t];
            for (int f2 = 0; f2 < EE; ++f2) bs += s_se[f2] * s_l1T[f2 * 65 + t];
            float r = fmaxf(bs, 0.f) * lin3_w[t];
            for (int o = 32; o; o >>= 1) r += __shfl_xor(r, o);
            if (t == 0) ws[OFF_S + b] = r + lin3_b[0];
        }
    }
}

// ---- epilogue: 1 row/wave, lin2 row in registers ----
__global__ __launch_bounds__(256) void k_out3(const float* __restrict__ lin2_w,
                                              const float* __restrict__ lin2_b,
                                              const float* __restrict__ lin3_w,
                                              const float* __restrict__ ws,
                                              float* __restrict__ out) {
    __shared__ float s_l2T[EE * 65];
    __shared__ float s_wgw[HH * EE];   // 0.25-folded
    __shared__ float s_S[BB];
    __shared__ float s_l2b[EE], s_l3[EE];
    const int t = threadIdx.x;
    const int w = t >> 6, lane = t & 63;
    for (int k = t; k < EE * EE; k += 256) {
        int fp = k >> 6, f = k & 63;
        s_l2T[f * 65 + fp] = lin2_w[k];
    }
    s_wgw[t] = 0.25f * ws[OFF_WGWST + t];
    if (t < BB) s_S[t] = ws[OFF_S + t];
    if (t < EE) { s_l2b[t] = lin2_b[t]; s_l3[t] = lin3_w[EE + t]; }
    __syncthreads();

    float lr[EE];
    #pragma unroll
    for (int f = 0; f < EE; ++f) lr[f] = s_l2T[f * 65 + lane];

    const int i = blockIdx.x * 4 + w;
    float xsws = ws[OFF_SWS + (size_t)i * EE + lane];
    float sa = (lane < 32) ? ws[OFF_SATT + i * 32 + lane] : 0.f;
    for (int b = 0; b < BB; ++b) {
        float xv = xsws;
        for (int h = 0; h < HH; ++h)
            xv += __shfl(sa, b * 4 + h) * s_wgw[h * EE + lane];
        xv = fmaxf(xv, 0.f);
        float acc = s_l2b[lane];
        #pragma unroll
        for (int f = 0; f < EE; ++f) acc += __shfl(xv, f) * lr[f];
        float r = fmaxf(acc, 0.f) * s_l3[lane];
        for (int o = 32; o; o >>= 1) r += __shfl_xor(r, o);
        if (lane == 0) out[(size_t)b * NN + i] = s_S[b] + r;
    }
}

extern "C" void kernel_launch(void* const* d_in, const int* in_sizes, int n_in,
                              void* d_out, int out_size, void* d_ws, size_t ws_size,
                              hipStream_t stream) {
    const float* state    = (const float*)d_in[0];
    const float* strucEmb = (const float*)d_in[1];
    const int*   adj      = (const int*)d_in[2];   // int32 {0,1}, verified r11/r13
    const float* W_gat    = (const float*)d_in[3];
    const float* att      = (const float*)d_in[4];
    const float* Ws       = (const float*)d_in[5];
    const float* Wst      = (const float*)d_in[6];
    const float* lin1_w   = (const float*)d_in[7];
    const float* lin1_b   = (const float*)d_in[8];
    const float* lin2_w   = (const float*)d_in[9];
    const float* lin2_b   = (const float*)d_in[10];
    const float* lin3_w   = (const float*)d_in[11];
    const float* lin3_b   = (const float*)d_in[12];
    float* ws = (float*)d_ws;
    float* out = (float*)d_out;   // f32 output, verified r13

    k_sws  <<<dim3(NN / 16),     dim3(256), 0, stream>>>(strucEmb, Ws, W_gat, att, Wst, ws);
    k_fsatt<<<dim3(NN),          dim3(256), 0, stream>>>(adj, state, ws);
    k_seS  <<<dim3(NCHUNK * BB), dim3(256), 0, stream>>>(lin1_w, lin1_b, lin3_w, lin3_b, ws);
    k_out3 <<<dim3(NN / 4),      dim3(256), 0, stream>>>(lin2_w, lin2_b, lin3_w, ws, out);
}

// Round 29
// 46.011 us; speedup vs baseline: 9.6644x; 1.3943x over previous
//
#include <hip/hip_runtime.h>

#define BB 8
#define NN 2048
#define HH 4
#define EE 64
#define MAXJ 128
#define NEG 0.2f
#define NCHUNK 32
#define NSWSB 128

static constexpr int OFF_WGWST = 8;                          // [4][64]
static constexpr int OFF_SWS   = 288;                        // [N][64]
static constexpr int OFF_SATT  = OFF_SWS + NN * EE;          // [N][32]
static constexpr int OFF_PART  = OFF_SATT + NN * 32;         // [NCHUNK*B][64]

// ---- stage 1: fsatt (blocks 0..2047) + sws (blocks 2048..2175), independent ----
__global__ __launch_bounds__(256) void k_front(const int* __restrict__ adj,
                                               const float* __restrict__ state,
                                               const float* __restrict__ strucEmb,
                                               const float* __restrict__ Ws,
                                               const float* __restrict__ W_gat,
                                               const float* __restrict__ att,
                                               const float* __restrict__ Wst,
                                               float* __restrict__ ws) {
    __shared__ float s_u[EE * 65 + 16 * EE];   // union: sws{wsT,emb} | fsatt{jq,jl,y}
    __shared__ float s_cs[HH], s_ct[HH];
    __shared__ int   s_c[4];
    __shared__ int   s_cnt;
    const int t = threadIdx.x;
    const int w = t >> 6, lane = t & 63;

    if (blockIdx.x >= NN) {
        // ---- sws path ----
        float* s_wsT = s_u;                 // [64*65]
        float* s_emb = s_u + EE * 65;       // [16*64]
        const int i0 = (blockIdx.x - NN) * 16;
        for (int k = t; k < EE * EE; k += 256)
            s_wsT[(k & 63) * 65 + (k >> 6)] = Ws[k];
        for (int k = t; k < 16 * EE; k += 256)
            s_emb[k] = strucEmb[(size_t)i0 * EE + k];
        __syncthreads();
        for (int q = 0; q < 4; ++q) {
            int r = w * 4 + q;
            float v = s_emb[r * EE + lane];
            float acc = 0.f;
            for (int e = 0; e < EE; ++e)
                acc += __shfl(v, e) * s_wsT[e * 65 + lane];
            ws[OFF_SWS + (size_t)(i0 + r) * EE + lane] = acc;
        }
        if (blockIdx.x == NN) {
            int h = t >> 6, f = t & 63;
            float acc = 0.f;
            for (int e = 0; e < EE; ++e) acc += W_gat[h * EE + e] * Wst[f * EE + e];
            ws[OFF_WGWST + t] = acc;
        }
        return;
    }

    // ---- fsatt path ----
    int*   jq = (int*)s_u;                  // [4][128]
    int*   jl = (int*)s_u + 4 * MAXJ;       // [128]
    float* yy = s_u + 5 * MAXJ;             // [8][128]
    const int i = blockIdx.x;

    if (t < 2 * HH) {   // inline cs/ct (8 lanes, 64-FMA chains; hidden by TLP)
        int h = t & 3;
        const float* wgx = W_gat + h * EE;
        const float* av  = att + h * 2 * EE + (t >= HH ? EE : 0);
        float a2 = 0.f;
        for (int e = 0; e < EE; ++e) a2 += wgx[e] * av[e];
        if (t < HH) s_cs[h] = a2; else s_ct[h] = a2;
    }
    {
        const int4* a4 = (const int4*)(adj + (size_t)i * NN) + w * 128;
        int base = 0;
        const unsigned long long below = (1ull << lane) - 1ull;
        for (int q = 0; q < 2; ++q) {
            int4 v = a4[q * 64 + lane];
            int j0 = w * 512 + (q * 64 + lane) * 4;
            int eb = (v.x == 0 ? 1 : 0) | (v.y == 0 ? 2 : 0) |
                     (v.z == 0 ? 4 : 0) | (v.w == 0 ? 8 : 0);
            unsigned long long b0 = __ballot(eb & 1), b1 = __ballot(eb & 2);
            unsigned long long b2 = __ballot(eb & 4), b3 = __ballot(eb & 8);
            int pos = base + __popcll(b0 & below) + __popcll(b1 & below)
                           + __popcll(b2 & below) + __popcll(b3 & below);
            if (eb & 1) { if (pos < MAXJ) jq[w * MAXJ + pos] = j0 + 0; ++pos; }
            if (eb & 2) { if (pos < MAXJ) jq[w * MAXJ + pos] = j0 + 1; ++pos; }
            if (eb & 4) { if (pos < MAXJ) jq[w * MAXJ + pos] = j0 + 2; ++pos; }
            if (eb & 8) { if (pos < MAXJ) jq[w * MAXJ + pos] = j0 + 3; ++pos; }
            base += __popcll(b0) + __popcll(b1) + __popcll(b2) + __popcll(b3);
        }
        if (lane == 0) s_c[w] = base > MAXJ ? MAXJ : base;
    }
    __syncthreads();
    {
        int start = 0;
        for (int q = 0; q < w; ++q) start += s_c[q];
        int cw = s_c[w];
        for (int k = lane; k < cw; k += 64) {
            int p = start + k;
            if (p < MAXJ) jl[p] = jq[w * MAXJ + k];
        }
        if (t == 0) {
            int tot = s_c[0] + s_c[1] + s_c[2] + s_c[3];
            s_cnt = tot > MAXJ ? MAXJ : tot;
        }
    }
    __syncthreads();
    const int cnt = s_cnt;

    for (int x = t; x < BB * MAXJ; x += 256) {
        int k = x & (MAXJ - 1);
        if (k < cnt) yy[x] = state[(x >> 7) * NN + jl[k]];
    }
    __syncthreads();

    int g = t >> 3, k0 = t & 7, b = g >> 2, h = g & 3;
    const float* yb = yy + b * MAXJ;
    float ct = s_ct[h];
    float si = state[b * NN + i] * s_cs[h];
    float mmax = -1e30f;
    for (int k = k0; k < cnt; k += 8) {
        float e = si + ct * yb[k]; e = e > 0.f ? e : NEG * e;
        mmax = fmaxf(mmax, e);
    }
    for (int o = 4; o; o >>= 1) mmax = fmaxf(mmax, __shfl_xor(mmax, o, 8));
    float den = 0.f, num = 0.f;
    for (int k = k0; k < cnt; k += 8) {
        float y = yb[k];
        float e = si + ct * y; e = e > 0.f ? e : NEG * e;
        float p = expf(e - mmax);
        den += p; num += p * y;
    }
    for (int o = 4; o; o >>= 1) { den += __shfl_xor(den, o, 8); num += __shfl_xor(num, o, 8); }
    if (k0 == 0) ws[OFF_SATT + i * 32 + g] = num / den;
}

// ---- stage 2: se partials (unchanged from r25) ----
__global__ void k_se(float* __restrict__ ws) {
    int b = blockIdx.x & 7, chunk = blockIdx.x >> 3;
    int t = threadIdx.x; // 256
    int f = t & 63, sl = t >> 6;
    float wgw[HH];
    for (int h = 0; h < HH; ++h) wgw[h] = 0.25f * ws[OFF_WGWST + h * EE + f];
    float acc = 0.f;
    int i0 = chunk * (NN / NCHUNK);
    for (int i = i0 + sl; i < i0 + NN / NCHUNK; i += 4) {
        float v = ws[OFF_SWS + i * EE + f];
        for (int h = 0; h < HH; ++h)
            v += ws[OFF_SATT + i * 32 + b * 4 + h] * wgw[h];
        acc += fmaxf(v, 0.f);
    }
    __shared__ float red[256];
    red[t] = acc;
    __syncthreads();
    if (t < EE)
        ws[OFF_PART + (size_t)blockIdx.x * EE + t] =
            red[t] + red[t + 64] + red[t + 128] + red[t + 192];
}

// ---- stage 3: fold PART -> S[b] per block (bitwise = old k_S), then epilogue ----
__global__ __launch_bounds__(256) void k_outS(const float* __restrict__ lin1_w,
                                              const float* __restrict__ lin1_b,
                                              const float* __restrict__ lin2_w,
                                              const float* __restrict__ lin2_b,
                                              const float* __restrict__ lin3_w,
                                              const float* __restrict__ lin3_b,
                                              const float* __restrict__ ws,
                                              float* __restrict__ out) {
    __shared__ float s_l1T[EE * 65];
    __shared__ float s_l2T[EE * 65];
    __shared__ float s_wgw[HH * EE];   // 0.25-folded
    __shared__ float s_se[BB * EE];
    __shared__ float s_S[BB];
    __shared__ float s_l2b[EE], s_l3[EE];
    const int t = threadIdx.x;
    const int w = t >> 6, lane = t & 63;
    for (int k = t; k < EE * EE; k += 256) {
        int o = k >> 6, f2 = k & 63;
        s_l1T[f2 * 65 + o] = lin1_w[k];
        s_l2T[f2 * 65 + o] = lin2_w[k];   // s_l2T[f][fp] = lin2_w[fp][f]
    }
    s_wgw[t] = 0.25f * ws[OFF_WGWST + t];
    if (t < EE) { s_l2b[t] = lin2_b[t]; s_l3[t] = lin3_w[EE + t]; }
    // se fold: ascending chunk order (bitwise = old k_S)
    for (int p = 0; p < 2; ++p) {
        int idx = p * 256 + t, b = idx >> 6, f = idx & 63;
        float se = 0.f;
        for (int c = 0; c < NCHUNK; ++c)
            se += ws[OFF_PART + (size_t)(c * BB + b) * EE + f];
        s_se[idx] = se;
    }
    __syncthreads();
    // S[b]: wave w handles b = w and b = w+4 (same matvec/butterfly order as k_S)
    for (int p = 0; p < 2; ++p) {
        int b = p * 4 + w;
        float bs = lin1_b[lane];
        for (int f2 = 0; f2 < EE; ++f2) bs += s_se[b * EE + f2] * s_l1T[f2 * 65 + lane];
        float r = fmaxf(bs, 0.f) * lin3_w[lane];
        for (int o = 32; o; o >>= 1) r += __shfl_xor(r, o);
        if (lane == 0) s_S[b] = r + lin3_b[0];
    }
    __syncthreads();

    float lr[EE];
    #pragma unroll
    for (int f = 0; f < EE; ++f) lr[f] = s_l2T[f * 65 + lane];

    const int i = blockIdx.x * 4 + w;
    float xsws = ws[OFF_SWS + (size_t)i * EE + lane];
    float sa = (lane < 32) ? ws[OFF_SATT + i * 32 + lane] : 0.f;
    for (int b = 0; b < BB; ++b) {
        float xv = xsws;
        for (int h = 0; h < HH; ++h)
            xv += __shfl(sa, b * 4 + h) * s_wgw[h * EE + lane];
        xv = fmaxf(xv, 0.f);
        float acc = s_l2b[lane];
        #pragma unroll
        for (int f = 0; f < EE; ++f) acc += __shfl(xv, f) * lr[f];
        float r = fmaxf(acc, 0.f) * s_l3[lane];
        for (int o = 32; o; o >>= 1) r += __shfl_xor(r, o);
        if (lane == 0) out[(size_t)b * NN + i] = s_S[b] + r;
    }
}

extern "C" void kernel_launch(void* const* d_in, const int* in_sizes, int n_in,
                              void* d_out, int out_size, void* d_ws, size_t ws_size,
                              hipStream_t stream) {
    const float* state    = (const float*)d_in[0];
    const float* strucEmb = (const float*)d_in[1];
    const int*   adj      = (const int*)d_in[2];   // int32 {0,1}, verified r11/r13
    const float* W_gat    = (const float*)d_in[3];
    const float* att      = (const float*)d_in[4];
    const float* Ws       = (const float*)d_in[5];
    const float* Wst      = (const float*)d_in[6];
    const float* lin1_w   = (const float*)d_in[7];
    const float* lin1_b   = (const float*)d_in[8];
    const float* lin2_w   = (const float*)d_in[9];
    const float* lin2_b   = (const float*)d_in[10];
    const float* lin3_w   = (const float*)d_in[11];
    const float* lin3_b   = (const float*)d_in[12];
    float* ws = (float*)d_ws;
    float* out = (float*)d_out;   // f32 output, verified r13

    k_front<<<dim3(NN + NSWSB), dim3(256), 0, stream>>>(adj, state, strucEmb, Ws,
                                                        W_gat, att, Wst, ws);
    k_se   <<<dim3(NCHUNK * BB), dim3(256), 0, stream>>>(ws);
    k_outS <<<dim3(NN / 4),      dim3(256), 0, stream>>>(lin1_w, lin1_b, lin2_w,
                                                         lin2_b, lin3_w, lin3_b, ws, out);
}